// Round 7
// baseline (4133.366 us; speedup 1.0000x reference)
//
#include <hip/hip_runtime.h>
#include <hip/hip_bf16.h>
#include <cstdio>

#define TT 512
#define NN 64
#define CC 512
#define HH 1024
#define PP 512
#define GG 4096           // 4*H
#define MPRE (TT*NN)      // 32768
#define TC 256            // timesteps per chunk
#define TCM (TC*NN)       // pre-chunk leading dim (rows)
#define NB 64             // recurrence blocks (16 h each)
#define FSTR 32           // flag padding: 32 dwords = 128 B = 1 L3 line per flag

typedef __attribute__((ext_vector_type(8))) short short8;
typedef __attribute__((ext_vector_type(4))) float floatx4;

__device__ __forceinline__ unsigned short f2bf(float f) {
  union { float f; unsigned u; } v; v.f = f;
  unsigned r = v.u + 0x7fffu + ((v.u >> 16) & 1u);
  return (unsigned short)(r >> 16);
}
__device__ __forceinline__ float bf2f(unsigned short u) {
  union { unsigned u; float f; } v; v.u = ((unsigned)u) << 16; return v.f;
}
__device__ __forceinline__ float sigm(float x) { return 1.f / (1.f + __expf(-x)); }
__device__ __forceinline__ float tanha(float x) { return 1.f - 2.f / (__expf(2.f * x) + 1.f); }

typedef const __attribute__((address_space(1))) void gvoid_t;
typedef __attribute__((address_space(3))) void lvoid_t;
__device__ __forceinline__ void gl2lds16(const void* g, void* l) {
  __builtin_amdgcn_global_load_lds((gvoid_t*)g, (lvoid_t*)l, 16, 0, 0);
}

__global__ void cast_f32_bf16(const float* __restrict__ src, unsigned short* __restrict__ dst, int n) {
  int i = (blockIdx.x * 256 + threadIdx.x) * 4;
  if (i < n) {
    float4 v = *(const float4*)(src + i);
    ushort4 o;
    o.x = f2bf(v.x); o.y = f2bf(v.y); o.z = f2bf(v.z); o.w = f2bf(v.w);
    *(ushort4*)(dst + i) = o;
  }
}

// dst[h][p] = (bf16) src[p][h]   (src is wo_w: P x H)
__global__ void transpose_cast(const float* __restrict__ src, unsigned short* __restrict__ dst) {
  int idx = blockIdx.x * 256 + threadIdx.x;
  if (idx < HH * PP) {
    int h = idx >> 9, p = idx & 511;
    dst[idx] = f2bf(src[p * HH + h]);
  }
}

// C[m][n] = sum_k A[m][k]*B[n][k] (+bias[n]); A: M x K, B: N x K, bf16.
// writeT: C stored transposed (C[n][m], leading dim M).
__global__ __launch_bounds__(256) void gemm_bt(
    const unsigned short* __restrict__ A, const unsigned short* __restrict__ B,
    const float* __restrict__ bias, unsigned short* __restrict__ C,
    int M, int N, int K, int writeT)
{
  __shared__ __align__(16) unsigned short As[128 * 32];
  __shared__ __align__(16) unsigned short Bs[128 * 32];
  const int tid = threadIdx.x;
  const int l = tid & 63, w = tid >> 6;
  const int wm = w >> 1, wn = w & 1;
  const int lane16 = l & 15, quad = l >> 4;
  const int rowA0 = blockIdx.x * 128, rowB0 = blockIdx.y * 128;
  floatx4 acc[4][4] = {};
  for (int kk = 0; kk < K; kk += 32) {
    __syncthreads();
#pragma unroll
    for (int r = 0; r < 2; ++r) {
      const int e = r * 256 + tid;
      const int row = e >> 2, kgrp = (e & 3) << 3;
      gl2lds16(A + (size_t)(rowA0 + row) * K + kk + kgrp, As + (r * 256 + w * 64) * 8);
      gl2lds16(B + (size_t)(rowB0 + row) * K + kk + kgrp, Bs + (r * 256 + w * 64) * 8);
    }
    __syncthreads();
    short8 af[4], bf[4];
#pragma unroll
    for (int mt = 0; mt < 4; ++mt) af[mt] = *(const short8*)&As[(wm * 64 + mt * 16 + lane16) * 32 + quad * 8];
#pragma unroll
    for (int nt = 0; nt < 4; ++nt) bf[nt] = *(const short8*)&Bs[(wn * 64 + nt * 16 + lane16) * 32 + quad * 8];
#pragma unroll
    for (int mt = 0; mt < 4; ++mt)
#pragma unroll
      for (int nt = 0; nt < 4; ++nt)
        acc[mt][nt] = __builtin_amdgcn_mfma_f32_16x16x32_bf16(af[mt], bf[nt], acc[mt][nt], 0, 0, 0);
  }
#pragma unroll
  for (int mt = 0; mt < 4; ++mt) {
    const int m0 = rowA0 + wm * 64 + mt * 16 + quad * 4;
#pragma unroll
    for (int nt = 0; nt < 4; ++nt) {
      const int col = rowB0 + wn * 64 + nt * 16 + lane16;
      const float bv = bias ? bias[col] : 0.f;
      if (writeT) {
        ushort4 o;
        o.x = f2bf(acc[mt][nt][0] + bv); o.y = f2bf(acc[mt][nt][1] + bv);
        o.z = f2bf(acc[mt][nt][2] + bv); o.w = f2bf(acc[mt][nt][3] + bv);
        *(ushort4*)(C + (size_t)col * M + m0) = o;
      } else {
#pragma unroll
        for (int j = 0; j < 4; ++j) C[(size_t)(m0 + j) * N + col] = f2bf(acc[mt][nt][j] + bv);
      }
    }
  }
}

// ---------------------------------------------------------------------------
// R7 = R4 (k-split wave mapping, Wc in registers, 2-deep act pipeline) with a
// trimmed serial chain:
//   - ALL waves poll the flags independently (no S4 on the readiness path);
//     each wave issues its act loads immediately on detect. Per-wave ordering
//     argument: act loads issue only after the flag load's data returned
//     (branch dependence), so they reach L3 after the flag was served there.
//   - flags padded to one per 128 B line (kills hot-line contention between
//     64 pollers and 64 writers).
//   - out-projection reduce+store moved into the NEXT iteration's act-load
//     shadow (r4 read at loop top; S4 barrier placed AFTER the read, hidden
//     under load latency, protects r4 against this iteration's re-write).
//     Boundary rows: break path stores row t1-2; post-loop stores row t1-1
//     (last chunk). Rows 0..511 each stored exactly once.
//
// act buffer layout (per parity, 16384 qwords = 128 KB):
//   qword idx = kgrp*128 + n*2 + half,  kgrp = k>>3 in [0,128), half = (k>>2)&1
//   qword holds act[n][k = kgrp*8 + half*4 + 0..3] as 4 bf16.
// Consumer wave w, (nt,kst): lane (lane16,quad) loads qwords
//   base_t + kst*512 + nt*32 + {0,1},  base_t = w*4096 + quad*128 + lane16*2
//   -> A-frag row n = nt*16+lane16, k = w*256+kst*32+quad*8 .. +8.
// Producer thread (b,w,l): h rows k = b*16+4w+0..3, n=l -> ONE 8 B store at
//   pq = (2b + (w>>1))*128 + l*2 + (w&1).
//
// Release protocol: act store -> s_waitcnt(0) -> S2 -> flags[b*FSTR] = t+1.
// ---------------------------------------------------------------------------
__global__ __launch_bounds__(256, 1) void lstm_rec(
    const unsigned short* __restrict__ preC,  // [4096][TCM] bf16
    const unsigned short* __restrict__ Wc,    // [4096][1024] bf16 (wr_w @ wo_w)
    const unsigned short* __restrict__ wo,    // [512][1024] bf16
    const float* __restrict__ wcp,            // [3072] peephole
    const void* __restrict__ lengths,         // int32 or int64 (auto-detected)
    unsigned long long* __restrict__ act2,    // [2][16384] qwords (zeroed)
    float* __restrict__ c_buf,                // [64][1024] f32 carry (zeroed)
    float* __restrict__ out,                  // [512][64][512]
    unsigned* __restrict__ flags,             // [NB*FSTR] zeroed, padded
    int t0, int t1, int last)
{
  __shared__ float g4[4][64][65];   // 66.6 KB partial gate sums
  __shared__ float r4[4][32][17];   // 8.7 KB partial out-proj sums
  const int tid = threadIdx.x, b = blockIdx.x;
  const int l = tid & 63, w = tid >> 6;
  const int lane16 = l & 15, quad = l >> 4;
  const int ptile = b & 31, kgr = b >> 5;     // out tile: n half kgr, p tile ptile
  const int ntA = 2 * kgr, ntB = ntA + 1;

  const int* L32 = (const int*)lengths;
  const bool is64 = (L32[1] == 0);

  // persistent Wc B-fragments for this wave's k-quarter (128 regs)
  short8 bbr[4][8];
#pragma unroll
  for (int gt = 0; gt < 4; ++gt)
#pragma unroll
    for (int kst = 0; kst < 8; ++kst)
      bbr[gt][kst] = *(const short8*)&Wc[(size_t)(gt * 1024 + b * 16 + lane16) * 1024
                                         + w * 256 + kst * 32 + quad * 8];

  const unsigned short* worow = wo + (size_t)(ptile * 16 + lane16) * 1024 + w * 256 + quad * 8;

  // gate-math thread (n=l, h = hb + kk, kk=0..3)
  const int hb = b * 16 + 4 * w;
  float cst[4], wci[4], wcf[4], wco[4];
#pragma unroll
  for (int kk = 0; kk < 4; ++kk) {
    cst[kk] = c_buf[l * HH + hb + kk];
    wci[kk] = wcp[hb + kk];
    wcf[kk] = wcp[1024 + hb + kk];
    wco[kk] = wcp[2048 + hb + kk];
  }
  const int base_t = w * 4096 + quad * 128 + lane16 * 2;        // consumer qword base
  const int pq = (2 * b + (w >> 1)) * 128 + l * 2 + (w & 1);    // producer qword slot

  // out-store thread mapping: n = kgr*32 + nr, p = ptile*16 + ph*2 + {0,1}
  const int nr = tid & 31, ph = tid >> 5;
  const int n_out = kgr * 32 + nr;
  const int ln_out = is64 ? (int)((const long long*)lengths)[n_out] : L32[n_out];
  const int pl0 = ph * 2;

  float pvc[4][4], pvn[4][4];
  {
    const int trel = l;  // (t0 - t0)*NN + l
#pragma unroll
    for (int g = 0; g < 4; ++g)
#pragma unroll
      for (int kk = 0; kk < 4; ++kk)
        pvc[g][kk] = bf2f(preC[(size_t)(g * 1024 + hb + kk) * TCM + trel]);
  }

#define LOADK(BUF, KST)                                                                  \
  _Pragma("unroll") for (int nt_ = 0; nt_ < 4; ++nt_) {                                  \
    Aq[BUF][nt_][0] = __hip_atomic_load(aPq + (KST) * 512 + nt_ * 32,                    \
                                        __ATOMIC_RELAXED, __HIP_MEMORY_SCOPE_AGENT);     \
    Aq[BUF][nt_][1] = __hip_atomic_load(aPq + (KST) * 512 + nt_ * 32 + 1,                \
                                        __ATOMIC_RELAXED, __HIP_MEMORY_SCOPE_AGENT);     \
  }

#define OUTSTORE(ROW)                                                                    \
  {                                                                                      \
    float o0 = r4[0][nr][pl0]     + r4[1][nr][pl0]     + r4[2][nr][pl0]     + r4[3][nr][pl0];     \
    float o1 = r4[0][nr][pl0 + 1] + r4[1][nr][pl0 + 1] + r4[2][nr][pl0 + 1] + r4[3][nr][pl0 + 1]; \
    if ((ROW) >= ln_out) { o0 = 0.f; o1 = 0.f; }                                         \
    *(float2*)&out[(size_t)((ROW) * NN + n_out) * PP + ptile * 16 + pl0] = make_float2(o0, o1);   \
  }

  for (int t = t0; t <= t1; ++t) {
    // non-last chunk: flush pending out row t1-2 (r4 from iteration t1-1), exit
    if (t == t1 && !last) {
      OUTSTORE(t - 2)      // t1 >= 256, row >= 0; r4 writes barrier-ordered by S1 of t1-1
      break;
    }
    const bool gate_on = (t < t1);
    const unsigned long long* aPq = act2 + (size_t)((t + 1) & 1) * 16384 + base_t;

    // ---- issue first act loads, then do deferred out-store in their shadow ----
    floatx4 accg4[4][4] = {};          // [nt][gt]
    floatx4 acco4[2] = {};             // nt = ntA, ntB
    unsigned long long Aq[2][4][2];
    LOADK(0, 0)

    if (t > t0 && t >= 2) OUTSTORE(t - 2)   // r4 from iteration t-1 (proj of h(t-2))
    __syncthreads();   // S4: r4 reads done before re-write below; hidden under load latency

#pragma unroll
    for (int kst = 0; kst < 8; ++kst) {
      if (kst < 7) LOADK((kst + 1) & 1, kst + 1)
      short8 wf = *(const short8*)(worow + kst * 32);
#pragma unroll
      for (int nt = 0; nt < 4; ++nt) {
        union { unsigned long long q[2]; short8 s; } u;
        u.q[0] = Aq[kst & 1][nt][0]; u.q[1] = Aq[kst & 1][nt][1];
#pragma unroll
        for (int gt = 0; gt < 4; ++gt)
          accg4[nt][gt] = __builtin_amdgcn_mfma_f32_16x16x32_bf16(u.s, bbr[gt][kst], accg4[nt][gt], 0, 0, 0);
        if (nt == ntA) acco4[0] = __builtin_amdgcn_mfma_f32_16x16x32_bf16(u.s, wf, acco4[0], 0, 0, 0);
        if (nt == ntB) acco4[1] = __builtin_amdgcn_mfma_f32_16x16x32_bf16(u.s, wf, acco4[1], 0, 0, 0);
      }
    }

    // out-proj partials to r4 (consumed at next iteration top / break / post-loop)
#pragma unroll
    for (int i = 0; i < 2; ++i)
#pragma unroll
      for (int j = 0; j < 4; ++j)
        r4[w][i * 16 + quad * 4 + j][lane16] = acco4[i][j];

    if (gate_on) {
      // dump gate partials: rows n = nt*16+quad*4+j, cols gc = gt*16+lane16
#pragma unroll
      for (int nt = 0; nt < 4; ++nt)
#pragma unroll
        for (int gt = 0; gt < 4; ++gt)
#pragma unroll
          for (int j = 0; j < 4; ++j)
            g4[w][nt * 16 + quad * 4 + j][gt * 16 + lane16] = accg4[nt][gt][j];
      __syncthreads();   // S1: r4 + g4 writes visible

      float hh[4];
      unsigned long long packed = 0;
#pragma unroll
      for (int kk = 0; kk < 4; ++kk) {
        const int c0 = 0 * 16 + 4 * w + kk, c1 = 1 * 16 + 4 * w + kk;
        const int c2 = 2 * 16 + 4 * w + kk, c3 = 3 * 16 + 4 * w + kk;
        float gi = g4[0][l][c0] + g4[1][l][c0] + g4[2][l][c0] + g4[3][l][c0] + pvc[0][kk];
        float gf = g4[0][l][c1] + g4[1][l][c1] + g4[2][l][c1] + g4[3][l][c1] + pvc[1][kk];
        float go = g4[0][l][c2] + g4[1][l][c2] + g4[2][l][c2] + g4[3][l][c2] + pvc[2][kk];
        float gc = g4[0][l][c3] + g4[1][l][c3] + g4[2][l][c3] + g4[3][l][c3] + pvc[3][kk];
        float ig = sigm(gi + wci[kk] * cst[kk]);
        float fg = sigm(gf + wcf[kk] * cst[kk]);
        float cc = fg * cst[kk] + ig * tanha(gc);
        float og = sigm(go + wco[kk] * cc);
        cst[kk] = cc;
        hh[kk] = og * tanha(cc);
        packed |= (unsigned long long)f2bf(hh[kk]) << (16 * kk);
      }
      __hip_atomic_store(act2 + (size_t)(t & 1) * 16384 + pq, packed,
                         __ATOMIC_RELAXED, __HIP_MEMORY_SCOPE_AGENT);

      __builtin_amdgcn_s_waitcnt(0);   // drain own coherent store
      __syncthreads();                 // S2: all waves drained
      if (tid == 0) {
        __atomic_signal_fence(__ATOMIC_SEQ_CST);
        __hip_atomic_store(&flags[b * FSTR], (unsigned)(t + 1),
                           __ATOMIC_RELAXED, __HIP_MEMORY_SCOPE_AGENT);
      }
      // prefetch peephole preactivations for t+1 (hidden under poll)
      if (t + 1 < t1) {
        const int trel = (t + 1 - t0) * NN + l;
#pragma unroll
        for (int g = 0; g < 4; ++g)
#pragma unroll
          for (int kk = 0; kk < 4; ++kk)
            pvn[g][kk] = bf2f(preC[(size_t)(g * 1024 + hb + kk) * TCM + trel]);
      }

      // ---- every wave polls; loads of t+1 issue immediately on detect ----
      {
        const unsigned tgt = (unsigned)(t + 1);
        while (1) {
          unsigned f = __hip_atomic_load(&flags[l * FSTR], __ATOMIC_RELAXED, __HIP_MEMORY_SCOPE_AGENT);
          if (__all(f >= tgt)) break;
          __builtin_amdgcn_s_sleep(1);
        }
        __atomic_signal_fence(__ATOMIC_SEQ_CST);
      }
      if (t + 1 < t1) {
#pragma unroll
        for (int g = 0; g < 4; ++g)
#pragma unroll
          for (int kk = 0; kk < 4; ++kk)
            pvc[g][kk] = pvn[g][kk];
      }
    }
  }

  if (last) {          // flush final out row t1-1 (r4 from gate_on=false iteration t1)
    __syncthreads();   // no S1 ran in that iteration; order r4 writes before reads
    OUTSTORE(t1 - 1)
  }
#pragma unroll
  for (int kk = 0; kk < 4; ++kk) c_buf[l * HH + hb + kk] = cst[kk];
#undef LOADK
#undef OUTSTORE
}

extern "C" void kernel_launch(void* const* d_in, const int* in_sizes, int n_in,
                              void* d_out, int out_size, void* d_ws, size_t ws_size,
                              hipStream_t stream) {
  (void)in_sizes; (void)n_in; (void)out_size;
  const float* x    = (const float*)d_in[0];
  const void*  len  = d_in[1];
  const float* wx_w = (const float*)d_in[2];
  const float* wx_b = (const float*)d_in[3];
  const float* wr_w = (const float*)d_in[4];
  const float* wo_w = (const float*)d_in[5];
  const float* wc   = (const float*)d_in[6];
  float* out = (float*)d_out;

  char* ws = (char*)d_ws; size_t off = 0;
  auto alloc = [&](size_t b) { void* p = ws + off; off += (b + 255) & ~(size_t)255; return p; };
  unsigned short* x_bf  = (unsigned short*)alloc((size_t)MPRE * CC * 2);
  unsigned short* wx_bf = (unsigned short*)alloc((size_t)GG * CC * 2);
  unsigned short* wr_bf = (unsigned short*)alloc((size_t)GG * PP * 2);
  unsigned short* wo_bf = (unsigned short*)alloc((size_t)PP * HH * 2);
  unsigned short* woT   = (unsigned short*)alloc((size_t)HH * PP * 2);
  unsigned short* Wc_bf = (unsigned short*)alloc((size_t)GG * HH * 2);
  unsigned short* preC  = (unsigned short*)alloc((size_t)GG * TCM * 2);
  unsigned long long* act2 = (unsigned long long*)alloc((size_t)2 * 16384 * 8);
  float*          c_buf = (float*)alloc((size_t)NN * HH * 4);
  unsigned* flags = (unsigned*)alloc((size_t)NB * FSTR * 4);
  if (off > ws_size) {
    fprintf(stderr, "kernel_launch: workspace too small (%zu needed, %zu given)\n", off, ws_size);
    return;
  }

  // zero act2 double-buffer (== h(-1)=0) + c carry + padded flags (contiguous)
  hipMemsetAsync(act2, 0, (size_t)2 * 16384 * 8 + (size_t)NN * HH * 4 + (size_t)NB * FSTR * 4, stream);

  int n1 = MPRE * CC; cast_f32_bf16<<<dim3((n1 / 4 + 255) / 256), dim3(256), 0, stream>>>(x, x_bf, n1);
  int n2 = GG * CC;   cast_f32_bf16<<<dim3((n2 / 4 + 255) / 256), dim3(256), 0, stream>>>(wx_w, wx_bf, n2);
  int n3 = GG * PP;   cast_f32_bf16<<<dim3((n3 / 4 + 255) / 256), dim3(256), 0, stream>>>(wr_w, wr_bf, n3);
  int n4 = PP * HH;   cast_f32_bf16<<<dim3((n4 / 4 + 255) / 256), dim3(256), 0, stream>>>(wo_w, wo_bf, n4);
  transpose_cast<<<dim3((HH * PP + 255) / 256), dim3(256), 0, stream>>>(wo_w, woT);

  // W_comb = wr_w @ wo_w  (4096 x 1024)
  gemm_bt<<<dim3(GG / 128, HH / 128), dim3(256), 0, stream>>>(wr_bf, woT, nullptr, Wc_bf, GG, HH, PP, 0);

  for (int chunk = 0; chunk < TT / TC; ++chunk) {
    const int t0 = chunk * TC, t1 = t0 + TC;
    const int last = (t1 == TT) ? 1 : 0;
    gemm_bt<<<dim3(TCM / 128, GG / 128), dim3(256), 0, stream>>>(
        x_bf + (size_t)t0 * NN * CC, wx_bf, wx_b, preC, TCM, GG, CC, 1);

    // plain launch: 64 blocks (1/CU) trivially co-resident on 256 CUs
    lstm_rec<<<dim3(NB), dim3(256), 0, stream>>>(
        preC, Wc_bf, wo_bf, wc, len, act2, c_buf, out, flags, t0, t1, last);
  }
}

// Round 8
// 3182.749 us; speedup vs baseline: 1.2987x; 1.2987x over previous
//
#include <hip/hip_runtime.h>
#include <hip/hip_bf16.h>
#include <cstdio>

#define TT 512
#define NN 64
#define CC 512
#define HH 1024
#define PP 512
#define GG 4096           // 4*H
#define MPRE (TT*NN)      // 32768
#define TC 256            // timesteps per chunk
#define TCM (TC*NN)       // pre-chunk leading dim (rows)
#define NB 64             // recurrence blocks (16 h each)

typedef __attribute__((ext_vector_type(8))) short short8;
typedef __attribute__((ext_vector_type(4))) float floatx4;

__device__ __forceinline__ unsigned short f2bf(float f) {
  union { float f; unsigned u; } v; v.f = f;
  unsigned r = v.u + 0x7fffu + ((v.u >> 16) & 1u);
  return (unsigned short)(r >> 16);
}
__device__ __forceinline__ float bf2f(unsigned short u) {
  union { unsigned u; float f; } v; v.u = ((unsigned)u) << 16; return v.f;
}
__device__ __forceinline__ float sigm(float x) { return 1.f / (1.f + __expf(-x)); }
__device__ __forceinline__ float tanha(float x) { return 1.f - 2.f / (__expf(2.f * x) + 1.f); }

typedef const __attribute__((address_space(1))) void gvoid_t;
typedef __attribute__((address_space(3))) void lvoid_t;
__device__ __forceinline__ void gl2lds16(const void* g, void* l) {
  __builtin_amdgcn_global_load_lds((gvoid_t*)g, (lvoid_t*)l, 16, 0, 0);
}

__global__ void cast_f32_bf16(const float* __restrict__ src, unsigned short* __restrict__ dst, int n) {
  int i = (blockIdx.x * 256 + threadIdx.x) * 4;
  if (i < n) {
    float4 v = *(const float4*)(src + i);
    ushort4 o;
    o.x = f2bf(v.x); o.y = f2bf(v.y); o.z = f2bf(v.z); o.w = f2bf(v.w);
    *(ushort4*)(dst + i) = o;
  }
}

// dst[h][p] = (bf16) src[p][h]   (src is wo_w: P x H)
__global__ void transpose_cast(const float* __restrict__ src, unsigned short* __restrict__ dst) {
  int idx = blockIdx.x * 256 + threadIdx.x;
  if (idx < HH * PP) {
    int h = idx >> 9, p = idx & 511;
    dst[idx] = f2bf(src[p * HH + h]);
  }
}

// C[m][n] = sum_k A[m][k]*B[n][k] (+bias[n]); A: M x K, B: N x K, bf16.
// writeT: C stored transposed (C[n][m], leading dim M).
__global__ __launch_bounds__(256) void gemm_bt(
    const unsigned short* __restrict__ A, const unsigned short* __restrict__ B,
    const float* __restrict__ bias, unsigned short* __restrict__ C,
    int M, int N, int K, int writeT)
{
  __shared__ __align__(16) unsigned short As[128 * 32];
  __shared__ __align__(16) unsigned short Bs[128 * 32];
  const int tid = threadIdx.x;
  const int l = tid & 63, w = tid >> 6;
  const int wm = w >> 1, wn = w & 1;
  const int lane16 = l & 15, quad = l >> 4;
  const int rowA0 = blockIdx.x * 128, rowB0 = blockIdx.y * 128;
  floatx4 acc[4][4] = {};
  for (int kk = 0; kk < K; kk += 32) {
    __syncthreads();
#pragma unroll
    for (int r = 0; r < 2; ++r) {
      const int e = r * 256 + tid;
      const int row = e >> 2, kgrp = (e & 3) << 3;
      gl2lds16(A + (size_t)(rowA0 + row) * K + kk + kgrp, As + (r * 256 + w * 64) * 8);
      gl2lds16(B + (size_t)(rowB0 + row) * K + kk + kgrp, Bs + (r * 256 + w * 64) * 8);
    }
    __syncthreads();
    short8 af[4], bf[4];
#pragma unroll
    for (int mt = 0; mt < 4; ++mt) af[mt] = *(const short8*)&As[(wm * 64 + mt * 16 + lane16) * 32 + quad * 8];
#pragma unroll
    for (int nt = 0; nt < 4; ++nt) bf[nt] = *(const short8*)&Bs[(wn * 64 + nt * 16 + lane16) * 32 + quad * 8];
#pragma unroll
    for (int mt = 0; mt < 4; ++mt)
#pragma unroll
      for (int nt = 0; nt < 4; ++nt)
        acc[mt][nt] = __builtin_amdgcn_mfma_f32_16x16x32_bf16(af[mt], bf[nt], acc[mt][nt], 0, 0, 0);
  }
#pragma unroll
  for (int mt = 0; mt < 4; ++mt) {
    const int m0 = rowA0 + wm * 64 + mt * 16 + quad * 4;
#pragma unroll
    for (int nt = 0; nt < 4; ++nt) {
      const int col = rowB0 + wn * 64 + nt * 16 + lane16;
      const float bv = bias ? bias[col] : 0.f;
      if (writeT) {
        ushort4 o;
        o.x = f2bf(acc[mt][nt][0] + bv); o.y = f2bf(acc[mt][nt][1] + bv);
        o.z = f2bf(acc[mt][nt][2] + bv); o.w = f2bf(acc[mt][nt][3] + bv);
        *(ushort4*)(C + (size_t)col * M + m0) = o;
      } else {
#pragma unroll
        for (int j = 0; j < 4; ++j) C[(size_t)(m0 + j) * N + col] = f2bf(acc[mt][nt][j] + bv);
      }
    }
  }
}

// ---------------------------------------------------------------------------
// R8 = R4 (k-split wave mapping, Wc in registers, 2-deep act pipeline,
// w0-poll flag protocol) with TRANSPOSED LDS reduction buffers:
//   g4[w][gatecol][n] (pad 68) and r4[w][pcol][n] (pad 36), so the MFMA
//   accumulator dump is ds_write_b128 of each floatx4 (16 vs 64 writes per
//   thread for g4) with start-banks spread over 8×4-bank residues (optimal
//   8 phases); reads are stride-1 (2-way, free).
//
// act buffer layout (per parity, 16384 qwords = 128 KB):
//   qword idx = kgrp*128 + n*2 + half,  kgrp = k>>3 in [0,128), half = (k>>2)&1
//   qword holds act[n][k = kgrp*8 + half*4 + 0..3] as 4 bf16.
// Consumer wave w, (nt,kst): lane (lane16,quad) loads qwords
//   base_t + kst*512 + nt*32 + {0,1},  base_t = w*4096 + quad*128 + lane16*2
//   -> A-frag row n = nt*16+lane16, k = w*256+kst*32+quad*8 .. +8.
// Producer thread (b,w,l): h rows k = b*16+4w+0..3, n=l -> ONE 8 B store at
//   pq = (2b + (w>>1))*128 + l*2 + (w&1).
//
// Sync protocol identical to R2/R4: store -> s_waitcnt(0) -> S2 ->
// flags[b]=t+1; wave 0 polls all 64 flags (1/lane, contiguous).
// ---------------------------------------------------------------------------
__global__ __launch_bounds__(256, 1) void lstm_rec(
    const unsigned short* __restrict__ preC,  // [4096][TCM] bf16
    const unsigned short* __restrict__ Wc,    // [4096][1024] bf16 (wr_w @ wo_w)
    const unsigned short* __restrict__ wo,    // [512][1024] bf16
    const float* __restrict__ wcp,            // [3072] peephole
    const void* __restrict__ lengths,         // int32 or int64 (auto-detected)
    unsigned long long* __restrict__ act2,    // [2][16384] qwords (zeroed)
    float* __restrict__ c_buf,                // [64][1024] f32 carry (zeroed)
    float* __restrict__ out,                  // [512][64][512]
    unsigned* __restrict__ flags,             // [NB] zeroed
    int t0, int t1, int last)
{
  __shared__ __align__(16) float g4[4][64][68];   // 69.6 KB  [wave][gatecol][n+pad]
  __shared__ __align__(16) float r4[4][16][36];   // 9.2 KB   [wave][pcol][n+pad]
  const int tid = threadIdx.x, b = blockIdx.x;
  const int l = tid & 63, w = tid >> 6;
  const int lane16 = l & 15, quad = l >> 4;
  const int ptile = b & 31, kgr = b >> 5;     // out tile: n half kgr, p tile ptile
  const int ntA = 2 * kgr, ntB = ntA + 1;

  const int* L32 = (const int*)lengths;
  const bool is64 = (L32[1] == 0);

  // persistent Wc B-fragments for this wave's k-quarter (128 regs)
  short8 bbr[4][8];
#pragma unroll
  for (int gt = 0; gt < 4; ++gt)
#pragma unroll
    for (int kst = 0; kst < 8; ++kst)
      bbr[gt][kst] = *(const short8*)&Wc[(size_t)(gt * 1024 + b * 16 + lane16) * 1024
                                         + w * 256 + kst * 32 + quad * 8];

  const unsigned short* worow = wo + (size_t)(ptile * 16 + lane16) * 1024 + w * 256 + quad * 8;

  // gate-math thread (n=l, h = hb + kk, kk=0..3)
  const int hb = b * 16 + 4 * w;
  float cst[4], wci[4], wcf[4], wco[4];
#pragma unroll
  for (int kk = 0; kk < 4; ++kk) {
    cst[kk] = c_buf[l * HH + hb + kk];
    wci[kk] = wcp[hb + kk];
    wcf[kk] = wcp[1024 + hb + kk];
    wco[kk] = wcp[2048 + hb + kk];
  }
  const int base_t = w * 4096 + quad * 128 + lane16 * 2;        // consumer qword base
  const int pq = (2 * b + (w >> 1)) * 128 + l * 2 + (w & 1);    // producer qword slot

  // out-store thread mapping: n = kgr*32 + nr, p = ptile*16 + ph*2 + {0,1}
  const int nr = tid & 31, ph = tid >> 5;
  const int n_out = kgr * 32 + nr;
  const int ln_out = is64 ? (int)((const long long*)lengths)[n_out] : L32[n_out];

  float pvc[4][4], pvn[4][4];
  {
    const int trel = l;  // (t0 - t0)*NN + l
#pragma unroll
    for (int g = 0; g < 4; ++g)
#pragma unroll
      for (int kk = 0; kk < 4; ++kk)
        pvc[g][kk] = bf2f(preC[(size_t)(g * 1024 + hb + kk) * TCM + trel]);
  }

#define LOADK(BUF, KST)                                                                  \
  _Pragma("unroll") for (int nt_ = 0; nt_ < 4; ++nt_) {                                  \
    Aq[BUF][nt_][0] = __hip_atomic_load(aPq + (KST) * 512 + nt_ * 32,                    \
                                        __ATOMIC_RELAXED, __HIP_MEMORY_SCOPE_AGENT);     \
    Aq[BUF][nt_][1] = __hip_atomic_load(aPq + (KST) * 512 + nt_ * 32 + 1,                \
                                        __ATOMIC_RELAXED, __HIP_MEMORY_SCOPE_AGENT);     \
  }

  for (int t = t0; t <= t1; ++t) {
    if (t == t1 && !last) break;
    const bool gate_on = (t < t1);
    const unsigned long long* aPq = act2 + (size_t)((t + 1) & 1) * 16384 + base_t;

    // ---- load + MFMA phase: gate partials (k-quarter) + out-proj partials ----
    // 2-deep in-flight pipeline (R4-proven).
    floatx4 accg4[4][4] = {};          // [nt][gt]
    floatx4 acco4[2] = {};             // nt = ntA, ntB
    unsigned long long Aq[2][4][2];
    LOADK(0, 0)
#pragma unroll
    for (int kst = 0; kst < 8; ++kst) {
      if (kst < 7) LOADK((kst + 1) & 1, kst + 1)
      short8 wf = *(const short8*)(worow + kst * 32);
#pragma unroll
      for (int nt = 0; nt < 4; ++nt) {
        union { unsigned long long q[2]; short8 s; } u;
        u.q[0] = Aq[kst & 1][nt][0]; u.q[1] = Aq[kst & 1][nt][1];
#pragma unroll
        for (int gt = 0; gt < 4; ++gt)
          accg4[nt][gt] = __builtin_amdgcn_mfma_f32_16x16x32_bf16(u.s, bbr[gt][kst], accg4[nt][gt], 0, 0, 0);
        if (nt == ntA) acco4[0] = __builtin_amdgcn_mfma_f32_16x16x32_bf16(u.s, wf, acco4[0], 0, 0, 0);
        if (nt == ntB) acco4[1] = __builtin_amdgcn_mfma_f32_16x16x32_bf16(u.s, wf, acco4[1], 0, 0, 0);
      }
    }

    if (gate_on) {
      // dump gate partials TRANSPOSED: g4[w][gatecol = gt*16+lane16][n = nt*16+quad*4 + 0..3]
      // one ds_write_b128 per (nt,gt); start banks = multiples of 4 -> 8 optimal phases
#pragma unroll
      for (int nt = 0; nt < 4; ++nt)
#pragma unroll
        for (int gt = 0; gt < 4; ++gt)
          *(floatx4*)&g4[w][gt * 16 + lane16][nt * 16 + quad * 4] = accg4[nt][gt];
      __syncthreads();   // S1

      float hh[4];
      unsigned long long packed = 0;
#pragma unroll
      for (int kk = 0; kk < 4; ++kk) {
        const int c0 = 0 * 16 + 4 * w + kk, c1 = 1 * 16 + 4 * w + kk;
        const int c2 = 2 * 16 + 4 * w + kk, c3 = 3 * 16 + 4 * w + kk;
        float gi = g4[0][c0][l] + g4[1][c0][l] + g4[2][c0][l] + g4[3][c0][l] + pvc[0][kk];
        float gf = g4[0][c1][l] + g4[1][c1][l] + g4[2][c1][l] + g4[3][c1][l] + pvc[1][kk];
        float go = g4[0][c2][l] + g4[1][c2][l] + g4[2][c2][l] + g4[3][c2][l] + pvc[2][kk];
        float gc = g4[0][c3][l] + g4[1][c3][l] + g4[2][c3][l] + g4[3][c3][l] + pvc[3][kk];
        float ig = sigm(gi + wci[kk] * cst[kk]);
        float fg = sigm(gf + wcf[kk] * cst[kk]);
        float cc = fg * cst[kk] + ig * tanha(gc);
        float og = sigm(go + wco[kk] * cc);
        cst[kk] = cc;
        hh[kk] = og * tanha(cc);
        packed |= (unsigned long long)f2bf(hh[kk]) << (16 * kk);
      }
      __hip_atomic_store(act2 + (size_t)(t & 1) * 16384 + pq, packed,
                         __ATOMIC_RELAXED, __HIP_MEMORY_SCOPE_AGENT);

      __builtin_amdgcn_s_waitcnt(0);   // drain own coherent store
      __syncthreads();                 // S2: all waves drained
      if (tid == 0) {
        __atomic_signal_fence(__ATOMIC_SEQ_CST);
        __hip_atomic_store(&flags[b], (unsigned)(t + 1),
                           __ATOMIC_RELAXED, __HIP_MEMORY_SCOPE_AGENT);
      }
      // prefetch peephole preactivations for t+1 (hidden under poll)
      if (t + 1 < t1) {
        const int trel = (t + 1 - t0) * NN + l;
#pragma unroll
        for (int g = 0; g < 4; ++g)
#pragma unroll
          for (int kk = 0; kk < 4; ++kk)
            pvn[g][kk] = bf2f(preC[(size_t)(g * 1024 + hb + kk) * TCM + trel]);
      }
    }

    // ---- out-projection reduction + store for step t-1 (overlaps poll) ----
    // dump TRANSPOSED: r4[w][pcol = lane16][n = i*16+quad*4 + 0..3], b128
#pragma unroll
    for (int i = 0; i < 2; ++i)
      *(floatx4*)&r4[w][lane16][i * 16 + quad * 4] = acco4[i];
    __syncthreads();   // S3
    if (t > 0) {
      const int pl0 = ph * 2;
      float o0 = r4[0][pl0][nr]     + r4[1][pl0][nr]     + r4[2][pl0][nr]     + r4[3][pl0][nr];
      float o1 = r4[0][pl0 + 1][nr] + r4[1][pl0 + 1][nr] + r4[2][pl0 + 1][nr] + r4[3][pl0 + 1][nr];
      if ((t - 1) >= ln_out) { o0 = 0.f; o1 = 0.f; }
      *(float2*)&out[(size_t)((t - 1) * NN + n_out) * PP + ptile * 16 + pl0] = make_float2(o0, o1);
    }

    if (gate_on) {
      if (w == 0) {
        const unsigned tgt = (unsigned)(t + 1);
        while (1) {
          unsigned f = __hip_atomic_load(&flags[l], __ATOMIC_RELAXED, __HIP_MEMORY_SCOPE_AGENT);
          if (__all(f >= tgt)) break;
          __builtin_amdgcn_s_sleep(1);
        }
        __atomic_signal_fence(__ATOMIC_SEQ_CST);
      }
      __syncthreads();   // S4
      if (t + 1 < t1) {
#pragma unroll
        for (int g = 0; g < 4; ++g)
#pragma unroll
          for (int kk = 0; kk < 4; ++kk)
            pvc[g][kk] = pvn[g][kk];
      }
    }
  }
#pragma unroll
  for (int kk = 0; kk < 4; ++kk) c_buf[l * HH + hb + kk] = cst[kk];
#undef LOADK
}

extern "C" void kernel_launch(void* const* d_in, const int* in_sizes, int n_in,
                              void* d_out, int out_size, void* d_ws, size_t ws_size,
                              hipStream_t stream) {
  (void)in_sizes; (void)n_in; (void)out_size;
  const float* x    = (const float*)d_in[0];
  const void*  len  = d_in[1];
  const float* wx_w = (const float*)d_in[2];
  const float* wx_b = (const float*)d_in[3];
  const float* wr_w = (const float*)d_in[4];
  const float* wo_w = (const float*)d_in[5];
  const float* wc   = (const float*)d_in[6];
  float* out = (float*)d_out;

  char* ws = (char*)d_ws; size_t off = 0;
  auto alloc = [&](size_t b) { void* p = ws + off; off += (b + 255) & ~(size_t)255; return p; };
  unsigned short* x_bf  = (unsigned short*)alloc((size_t)MPRE * CC * 2);
  unsigned short* wx_bf = (unsigned short*)alloc((size_t)GG * CC * 2);
  unsigned short* wr_bf = (unsigned short*)alloc((size_t)GG * PP * 2);
  unsigned short* wo_bf = (unsigned short*)alloc((size_t)PP * HH * 2);
  unsigned short* woT   = (unsigned short*)alloc((size_t)HH * PP * 2);
  unsigned short* Wc_bf = (unsigned short*)alloc((size_t)GG * HH * 2);
  unsigned short* preC  = (unsigned short*)alloc((size_t)GG * TCM * 2);
  unsigned long long* act2 = (unsigned long long*)alloc((size_t)2 * 16384 * 8);
  float*          c_buf = (float*)alloc((size_t)NN * HH * 4);
  unsigned* flags = (unsigned*)alloc(512);
  if (off > ws_size) {
    fprintf(stderr, "kernel_launch: workspace too small (%zu needed, %zu given)\n", off, ws_size);
    return;
  }

  // zero act2 double-buffer (== h(-1)=0) + c carry + flags (contiguous region)
  hipMemsetAsync(act2, 0, (size_t)2 * 16384 * 8 + (size_t)NN * HH * 4 + 512, stream);

  int n1 = MPRE * CC; cast_f32_bf16<<<dim3((n1 / 4 + 255) / 256), dim3(256), 0, stream>>>(x, x_bf, n1);
  int n2 = GG * CC;   cast_f32_bf16<<<dim3((n2 / 4 + 255) / 256), dim3(256), 0, stream>>>(wx_w, wx_bf, n2);
  int n3 = GG * PP;   cast_f32_bf16<<<dim3((n3 / 4 + 255) / 256), dim3(256), 0, stream>>>(wr_w, wr_bf, n3);
  int n4 = PP * HH;   cast_f32_bf16<<<dim3((n4 / 4 + 255) / 256), dim3(256), 0, stream>>>(wo_w, wo_bf, n4);
  transpose_cast<<<dim3((HH * PP + 255) / 256), dim3(256), 0, stream>>>(wo_w, woT);

  // W_comb = wr_w @ wo_w  (4096 x 1024)
  gemm_bt<<<dim3(GG / 128, HH / 128), dim3(256), 0, stream>>>(wr_bf, woT, nullptr, Wc_bf, GG, HH, PP, 0);

  for (int chunk = 0; chunk < TT / TC; ++chunk) {
    const int t0 = chunk * TC, t1 = t0 + TC;
    const int last = (t1 == TT) ? 1 : 0;
    gemm_bt<<<dim3(TCM / 128, GG / 128), dim3(256), 0, stream>>>(
        x_bf + (size_t)t0 * NN * CC, wx_bf, wx_b, preC, TCM, GG, CC, 1);

    // plain launch: 64 blocks (1/CU) trivially co-resident on 256 CUs
    lstm_rec<<<dim3(NB), dim3(256), 0, stream>>>(
        preC, Wc_bf, wo_bf, wc, len, act2, c_buf, out, flags, t0, t1, last);
  }
}